// Round 1
// 256.830 us; speedup vs baseline: 1.0415x; 1.0415x over previous
//
#include <hip/hip_runtime.h>
#include <cfloat>

#define N_PTS 8192
#define DTOK 256
#define KNN 16

typedef __attribute__((ext_vector_type(8))) short short8;
typedef __attribute__((ext_vector_type(4))) float float4v;

__device__ inline short f2bf(float f) {   // RTNE fp32 -> bf16
  unsigned u = __float_as_uint(f);
  u += 0x7fffu + ((u >> 16) & 1u);
  return (short)(u >> 16);
}
__device__ inline float bf2f(short h) {
  return __uint_as_float(((unsigned)(unsigned short)h) << 16);
}

// ---------------------------------------------------------------------------
// Pack xyz -> (x,y,z,sq) with the exact rounding the old knn used, so all
// distances (and thus KNN indices) are bit-identical.
// ---------------------------------------------------------------------------
__global__ __launch_bounds__(256) void knn_prep_kernel(
    const float* __restrict__ xyz, float4* __restrict__ xyz4) {
  const int i = blockIdx.x * 256 + threadIdx.x;
  float x = xyz[3 * i], y = xyz[3 * i + 1], z = xyz[3 * i + 2];
  float sq = __fadd_rn(__fadd_rn(__fmul_rn(x, x), __fmul_rn(y, y)),
                       __fmul_rn(z, z));
  xyz4[i] = make_float4(x, y, z, sq);
}

// Bit-exact candidate distance (round-explicit; identical in both passes).
__device__ inline float cand_dist(const float4 p, float xi, float yi, float zi,
                                  float sqi, int j, int i) {
  const float dot = fmaf(zi, p.z, fmaf(yi, p.y, __fmul_rn(xi, p.x)));
  float d = __fadd_rn(__fsub_rn(sqi, __fmul_rn(2.0f, dot)), p.w);
  if (j == i) d = __fadd_rn(d, 1e10f);
  return d;
}

// ---------------------------------------------------------------------------
// KNN v5: two-pass threshold, wave-per-point.
// Pass A: per-lane min over that lane's 128 candidates (no cross-lane work),
// then a 64-lane bitonic sort of the lane-mins. t = 16th-smallest lane-min is
// a PROVABLE upper bound on the true 16th-smallest distance (the 16 smallest
// lane-mins are themselves 16 distinct candidates with d <= t), with expected
// global rank ~18. Pass B: re-stream; only ~18-25 survivors (d<=t) enter the
// wave-serial stable insert (vs ~116 before) -- the insert chain was the
// measured bottleneck (VALUBusy 47%, HBM 0.2%, 81 us). Insert semantics are
// unchanged (strict d < s15, stable ascending-j order), so the output top-16
// is bit-identical; t only prunes candidates provably outside the top-16.
// ---------------------------------------------------------------------------
__global__ __launch_bounds__(256) void knn_select_kernel(
    const float4* __restrict__ xyz4, int* __restrict__ nbr) {
  const int lane = threadIdx.x & 63;
  const int i = blockIdx.x * 4 + (threadIdx.x >> 6);

  const float4 pi = xyz4[i];
  const float xi = pi.x, yi = pi.y, zi = pi.z, sqi = pi.w;

  // ---- pass A: per-lane running min ----
  float lmin = FLT_MAX;
  #pragma unroll 4
  for (int base = 0; base < N_PTS; base += 64) {
    const int j = base + lane;
    const float4 p = xyz4[j];
    lmin = fminf(lmin, cand_dist(p, xi, yi, zi, sqi, j, i));
  }

  // ---- 64-lane bitonic sort (ascending) of the lane-mins ----
  float v = lmin;
  #pragma unroll
  for (int k = 2; k <= 64; k <<= 1) {
    #pragma unroll
    for (int j = k >> 1; j > 0; j >>= 1) {
      const float o = __shfl_xor(v, j, 64);
      const bool up = ((lane & k) == 0);
      const bool lo = ((lane & j) == 0);
      v = (up == lo) ? fminf(v, o) : fmaxf(v, o);
    }
  }
  const float t = __shfl(v, 15, 64);   // >= true 16th-smallest distance

  // ---- pass B: stream again; only survivors hit the serial insert ----
  float sd = FLT_MAX;      // slot distance (lanes 0..15 meaningful)
  int sj = 0;              // slot index
  float s15 = FLT_MAX;     // current 16th-best (uniform)

  for (int base = 0; base < N_PTS; base += 64) {
    const int j = base + lane;
    const float4 p = xyz4[j];
    const float d = cand_dist(p, xi, yi, zi, sqi, j, i);

    unsigned long long m = __ballot((d < s15) && (d <= t));
    while (m) {                          // m is wave-uniform
      const int src = __ffsll(m) - 1;    // ascending lane == ascending j
      m &= m - 1;
      const float dc = __shfl(d, src);
      if (dc < s15) {                    // recheck vs tightened bound
        const int jc = base + src;
        const unsigned long long bm = __ballot(sd <= dc) & 0xFFFFull;
        const int pos = (int)__popcll(bm);      // stable position
        const float pu = __shfl_up(sd, 1);
        const int ju = __shfl_up(sj, 1);
        if (lane < 16) {
          if (lane > pos)        { sd = pu; sj = ju; }
          else if (lane == pos)  { sd = dc; sj = jc; }
        }
        s15 = __shfl(sd, 15);
      }
    }
  }
  if (lane < 16) nbr[i * KNN + lane] = sj;
}

// ---------------------------------------------------------------------------
// W1 -> Bt (transposed, n-major) bf16 hi/lo (frozen).
// ---------------------------------------------------------------------------
__global__ __launch_bounds__(256) void convert_w_kernel(
    const float* __restrict__ W1, short* __restrict__ bhi,
    short* __restrict__ blo) {
  const int n = blockIdx.x;      // 0..511
  const int k = threadIdx.x;     // 0..255
  const float v = (n < 256) ? W1[k * DTOK + n]
                            : W1[(259 + k) * DTOK + (n - 256)];
  short h = f2bf(v);
  bhi[n * 256 + k] = h;
  blo[n * 256 + k] = f2bf(v - bf2f(h));
}

// ---------------------------------------------------------------------------
// pq GEMM v2 (frozen from R9).
// ---------------------------------------------------------------------------
__global__ __launch_bounds__(256, 2) void pq_gemm_fused_kernel(
    const float* __restrict__ A, const short* __restrict__ Bthi,
    const short* __restrict__ Btlo, const float* __restrict__ xyz,
    const float* __restrict__ W1, const float* __restrict__ b1,
    float* __restrict__ R, float* __restrict__ Q) {
  __shared__ short Ahi[64][32], Alo[64][32];    // 4K + 4K
  __shared__ short Bhi[128][32], Blo[128][32];  // 8K + 8K
  __shared__ float Qs[64][65];                  // 16.6K
  __shared__ float sx[64][3];
  __shared__ float swz[6][64];
  __shared__ float sb1[64];

  const int tid = threadIdx.x;
  const int lane = tid & 63;
  const int wave = tid >> 6;
  const int l15 = lane & 15;
  const int quad = lane >> 4;
  const int mh = wave & 1;
  const int qh = wave >> 1;
  const int m0 = blockIdx.x * 64;
  const int np0 = blockIdx.y * 64;

  if (tid < 64) {
    sx[tid][0] = xyz[(m0 + tid) * 3];
    sx[tid][1] = xyz[(m0 + tid) * 3 + 1];
    sx[tid][2] = xyz[(m0 + tid) * 3 + 2];
  } else if (tid < 128) {
    int n = tid - 64;
    sb1[n] = b1[np0 + n];
    #pragma unroll
    for (int r = 0; r < 3; ++r) {
      swz[r][n] = W1[(256 + r) * DTOK + np0 + n];
      swz[3 + r][n] = W1[(515 + r) * DTOK + np0 + n];
    }
  }

  float4v acc[2][4];
  #pragma unroll
  for (int mf = 0; mf < 2; ++mf)
    #pragma unroll
    for (int nf = 0; nf < 4; ++nf)
      #pragma unroll
      for (int e = 0; e < 4; ++e) acc[mf][nf][e] = 0.f;

  const int ar = tid >> 2;             // A staging row 0..63
  const int ak = (tid & 3) * 8;        // A staging k-offset

  #pragma unroll 1
  for (int kc = 0; kc < 8; ++kc) {
    const int k0 = kc * 32;
    __syncthreads();
    {
      const float* asrc = A + (size_t)(m0 + ar) * 256 + k0 + ak;
      float4 a0 = *(const float4*)asrc;
      float4 a1 = *(const float4*)(asrc + 4);
      float v[8] = {a0.x, a0.y, a0.z, a0.w, a1.x, a1.y, a1.z, a1.w};
      short8 h8, l8;
      #pragma unroll
      for (int e = 0; e < 8; ++e) {
        short h = f2bf(v[e]);
        h8[e] = h;
        l8[e] = f2bf(v[e] - bf2f(h));
      }
      *(short8*)(&Ahi[ar][ak]) = h8;
      *(short8*)(&Alo[ar][ak]) = l8;
    }
    #pragma unroll
    for (int l = 0; l < 4; ++l) {
      const int rem = tid + 256 * (l & 1);
      const int row = rem >> 2;
      const int koff = (rem & 3) * 8;
      const int n = (row < 64) ? (np0 + row) : (256 + np0 + row - 64);
      const short* src = ((l < 2) ? Bthi : Btlo) + (size_t)n * 256 + k0 + koff;
      short8 vv = *(const short8*)src;
      if (l < 2) *(short8*)(&Bhi[row][koff]) = vv;
      else       *(short8*)(&Blo[row][koff]) = vv;
    }
    __syncthreads();

    short8 ah[2], al[2], bh[4], bl[4];
    #pragma unroll
    for (int mf = 0; mf < 2; ++mf) {
      ah[mf] = *(const short8*)(&Ahi[mh * 32 + mf * 16 + l15][quad * 8]);
      al[mf] = *(const short8*)(&Alo[mh * 32 + mf * 16 + l15][quad * 8]);
    }
    #pragma unroll
    for (int nf = 0; nf < 4; ++nf) {
      bh[nf] = *(const short8*)(&Bhi[qh * 64 + nf * 16 + l15][quad * 8]);
      bl[nf] = *(const short8*)(&Blo[qh * 64 + nf * 16 + l15][quad * 8]);
    }
    #pragma unroll
    for (int mf = 0; mf < 2; ++mf)
      #pragma unroll
      for (int nf = 0; nf < 4; ++nf) {
        acc[mf][nf] = __builtin_amdgcn_mfma_f32_16x16x32_bf16(
            ah[mf], bh[nf], acc[mf][nf], 0, 0, 0);
        acc[mf][nf] = __builtin_amdgcn_mfma_f32_16x16x32_bf16(
            ah[mf], bl[nf], acc[mf][nf], 0, 0, 0);
        acc[mf][nf] = __builtin_amdgcn_mfma_f32_16x16x32_bf16(
            al[mf], bh[nf], acc[mf][nf], 0, 0, 0);
      }
  }

  if (qh == 1) {
    #pragma unroll
    for (int mf = 0; mf < 2; ++mf)
      #pragma unroll
      for (int nf = 0; nf < 4; ++nf)
        #pragma unroll
        for (int e = 0; e < 4; ++e) {
          int row = mh * 32 + mf * 16 + quad * 4 + e;
          int col = nf * 16 + l15;
          float q = acc[mf][nf][e] + sx[row][0] * swz[3][col] +
                    sx[row][1] * swz[4][col] + sx[row][2] * swz[5][col];
          Qs[row][col] = q;
          Q[(size_t)(m0 + row) * DTOK + np0 + col] = q;
        }
  }
  __syncthreads();
  if (qh == 0) {
    #pragma unroll
    for (int mf = 0; mf < 2; ++mf)
      #pragma unroll
      for (int nf = 0; nf < 4; ++nf)
        #pragma unroll
        for (int e = 0; e < 4; ++e) {
          int row = mh * 32 + mf * 16 + quad * 4 + e;
          int col = nf * 16 + l15;
          float p = acc[mf][nf][e] + sx[row][0] * swz[0][col] +
                    sx[row][1] * swz[1][col] + sx[row][2] * swz[2][col];
          R[(size_t)(m0 + row) * DTOK + np0 + col] =
              (p + sb1[col]) - Qs[row][col];
        }
  }
}

// ---------------------------------------------------------------------------
// EdgeConv via MFMA (EXACT R10 version -- R11's global-B variant regressed
// 68 -> ~110 us/launch; W2 register fragments restored).
// ---------------------------------------------------------------------------
#define EP 8          // points per group

__global__ __launch_bounds__(256, 2) void edge_mfma_kernel(
    const float* __restrict__ R, const float* __restrict__ Q,
    const int* __restrict__ nbr, const float* __restrict__ W2,
    const float* __restrict__ b2, float* __restrict__ out,
    int num_groups, int groups_per_block) {
  __shared__ short Hs[EP * KNN * DTOK];   // 128 rows x 256, 64 KB
  const int lane = threadIdx.x & 63;
  const int wave = threadIdx.x >> 6;
  const int l15 = lane & 15;
  const int quad = lane >> 4;

  short8 bfr[4][8];
  #pragma unroll
  for (int nt_i = 0; nt_i < 4; ++nt_i) {
    const int n = (wave * 4 + nt_i) * 16 + l15;
    #pragma unroll
    for (int kt = 0; kt < 8; ++kt) {
      short8 f;
      #pragma unroll
      for (int jj = 0; jj < 8; ++jj) {
        int k = kt * 32 + quad * 8 + jj;
        f[jj] = f2bf(W2[k * DTOK + n]);
      }
      bfr[nt_i][kt] = f;
    }
  }

  const int wc8 = lane >> 1;
  const int wsub = (lane & 1) * 4;

  for (int gi = 0; gi < groups_per_block; ++gi) {
    const int g = blockIdx.x + gi * gridDim.x;
    if (g >= num_groups) break;
    const int i0 = g * EP;

    // ---- build H: prefetched nbr via lane reg + shfl, pipelined gathers ----
    {
      const int ia = i0 + wave * 2;
      const int jr0 = nbr[ia * KNN + l15];
      const int jr1 = nbr[(ia + 1) * KNN + l15];
      const float4 ri0 = ((const float4*)(R + (size_t)ia * DTOK))[lane];
      const float4 ri1 = ((const float4*)(R + (size_t)(ia + 1) * DTOK))[lane];
      #pragma unroll
      for (int pp = 0; pp < 2; ++pp) {
        const float4 ri = pp ? ri1 : ri0;
        const int jr = pp ? jr1 : jr0;
        #pragma unroll
        for (int k = 0; k < KNN; ++k) {
          const int j = __shfl(jr, k, 16);
          const float4 qj = ((const float4*)(Q + (size_t)j * DTOK))[lane];
          const int r = wave * 32 + pp * 16 + k;
          uint2 pk;
          pk.x = ((unsigned)(unsigned short)f2bf(fmaxf(ri.x + qj.x, 0.f))) |
                 (((unsigned)(unsigned short)f2bf(fmaxf(ri.y + qj.y, 0.f))) << 16);
          pk.y = ((unsigned)(unsigned short)f2bf(fmaxf(ri.z + qj.z, 0.f))) |
                 (((unsigned)(unsigned short)f2bf(fmaxf(ri.w + qj.w, 0.f))) << 16);
          *(uint2*)(&Hs[r * DTOK + ((wc8 ^ (r & 7)) << 3) + wsub]) = pk;
        }
      }
    }
    __syncthreads();

    #pragma unroll
    for (int mp = 0; mp < 4; ++mp) {
      float4v acc[2][4];
      #pragma unroll
      for (int mi = 0; mi < 2; ++mi)
        #pragma unroll
        for (int nt_i = 0; nt_i < 4; ++nt_i)
          #pragma unroll
          for (int e = 0; e < 4; ++e) acc[mi][nt_i][e] = 0.f;

      #pragma unroll
      for (int kt = 0; kt < 8; ++kt) {
        const int pc = ((kt * 4 + quad) ^ (l15 & 7)) << 3;
        const short8 a0 = *(const short8*)(
            &Hs[((mp * 2 + 0) * 16 + l15) * DTOK + pc]);
        const short8 a1 = *(const short8*)(
            &Hs[((mp * 2 + 1) * 16 + l15) * DTOK + pc]);
        #pragma unroll
        for (int nt_i = 0; nt_i < 4; ++nt_i) {
          acc[0][nt_i] = __builtin_amdgcn_mfma_f32_16x16x32_bf16(
              a0, bfr[nt_i][kt], acc[0][nt_i], 0, 0, 0);
          acc[1][nt_i] = __builtin_amdgcn_mfma_f32_16x16x32_bf16(
              a1, bfr[nt_i][kt], acc[1][nt_i], 0, 0, 0);
        }
      }

      #pragma unroll
      for (int mi = 0; mi < 2; ++mi) {
        #pragma unroll
        for (int nt_i = 0; nt_i < 4; ++nt_i) {
          float rm = fmaxf(fmaxf(acc[mi][nt_i][0], acc[mi][nt_i][1]),
                           fmaxf(acc[mi][nt_i][2], acc[mi][nt_i][3]));
          rm = fmaxf(rm, __shfl_xor(rm, 16, 64));
          rm = fmaxf(rm, __shfl_xor(rm, 32, 64));
          if (lane < 16) {
            const int i = i0 + mp * 2 + mi;
            const int n = (wave * 4 + nt_i) * 16 + lane;
            out[(size_t)i * DTOK + n] = rm + b2[n];
          }
        }
      }
    }
    __syncthreads();
  }
}

// ---------------------------------------------------------------------------
extern "C" void kernel_launch(void* const* d_in, const int* in_sizes, int n_in,
                              void* d_out, int out_size, void* d_ws,
                              size_t ws_size, hipStream_t stream) {
  const float* xyz = (const float*)d_in[0];
  const float* feat = (const float*)d_in[1];
  const float* W1a = (const float*)d_in[2];
  const float* b1a = (const float*)d_in[3];
  const float* W2a = (const float*)d_in[4];
  const float* b2a = (const float*)d_in[5];
  const float* W1b = (const float*)d_in[6];
  const float* b1b = (const float*)d_in[7];
  const float* W2b = (const float*)d_in[8];
  const float* b2b = (const float*)d_in[9];
  float* out = (float*)d_out;

  // ws layout (~25 MB): nbr 0.5 | xyz4 128KB (then R at +8MB) | Q | Bt hi/lo
  char* w = (char*)d_ws;
  const size_t SZ_NBR = (size_t)N_PTS * KNN * sizeof(int);        // 512 KB
  const size_t MB = 1024 * 1024;
  int* nbr = (int*)w;
  char* w1 = w + SZ_NBR;
  float4* xyz4 = (float4*)w1;                  // 128 KB
  float* R = (float*)(w1 + 8 * MB);            // 8 MB
  float* Q = (float*)(w + SZ_NBR + 16 * MB);   // 8 MB
  short* Bthi = (short*)(w + SZ_NBR + 24 * MB);// 256 KB
  short* Btlo = Bthi + 512 * 256;              // 256 KB
  float* bufC = out;                           // layer-a output staging

  knn_prep_kernel<<<N_PTS / 256, 256, 0, stream>>>(xyz, xyz4);
  knn_select_kernel<<<N_PTS / 4, 256, 0, stream>>>(xyz4, nbr);

  const int num_groups = N_PTS / EP;           // 1024
  const int nblocks = 512;

  // layer a
  convert_w_kernel<<<512, 256, 0, stream>>>(W1a, Bthi, Btlo);
  pq_gemm_fused_kernel<<<dim3(N_PTS / 64, 4), 256, 0, stream>>>(
      feat, Bthi, Btlo, xyz, W1a, b1a, R, Q);
  edge_mfma_kernel<<<nblocks, 256, 0, stream>>>(R, Q, nbr, W2a, b2a, bufC,
                                                num_groups, 2);

  // layer b
  convert_w_kernel<<<512, 256, 0, stream>>>(W1b, Bthi, Btlo);
  pq_gemm_fused_kernel<<<dim3(N_PTS / 64, 4), 256, 0, stream>>>(
      bufC, Bthi, Btlo, xyz, W1b, b1b, R, Q);
  edge_mfma_kernel<<<nblocks, 256, 0, stream>>>(R, Q, nbr, W2b, b2b, out,
                                                num_groups, 2);
}

// Round 2
// 240.156 us; speedup vs baseline: 1.1138x; 1.0694x over previous
//
#include <hip/hip_runtime.h>
#include <cfloat>

#define N_PTS 8192
#define DTOK 256
#define KNN 16

typedef __attribute__((ext_vector_type(8))) short short8;
typedef __attribute__((ext_vector_type(4))) float float4v;

__device__ inline short f2bf(float f) {   // RTNE fp32 -> bf16
  unsigned u = __float_as_uint(f);
  u += 0x7fffu + ((u >> 16) & 1u);
  return (short)(u >> 16);
}
__device__ inline float bf2f(short h) {
  return __uint_as_float(((unsigned)(unsigned short)h) << 16);
}

// ---------------------------------------------------------------------------
// Pack xyz -> (x,y,z,sq) with the exact rounding the old knn used, so all
// distances (and thus KNN indices) are bit-identical.
// ---------------------------------------------------------------------------
__global__ __launch_bounds__(256) void knn_prep_kernel(
    const float* __restrict__ xyz, float4* __restrict__ xyz4) {
  const int i = blockIdx.x * 256 + threadIdx.x;
  float x = xyz[3 * i], y = xyz[3 * i + 1], z = xyz[3 * i + 2];
  float sq = __fadd_rn(__fadd_rn(__fmul_rn(x, x), __fmul_rn(y, y)),
                       __fmul_rn(z, z));
  xyz4[i] = make_float4(x, y, z, sq);
}

// Bit-exact candidate distance (round-explicit; identical in both passes).
__device__ inline float cand_dist(const float4 p, float xi, float yi, float zi,
                                  float sqi, int j, int i) {
  const float dot = fmaf(zi, p.z, fmaf(yi, p.y, __fmul_rn(xi, p.x)));
  float d = __fadd_rn(__fsub_rn(sqi, __fmul_rn(2.0f, dot)), p.w);
  if (j == i) d = __fadd_rn(d, 1e10f);
  return d;
}

// ---------------------------------------------------------------------------
// KNN v6: two-pass threshold + BLOCK-SHARED LDS candidate staging.
// R1 post-mortem: v5 was L2-BW-bound -- each of 8192 waves re-read the whole
// 128KB xyz4 per pass from L2 (2.1 GB total ~= 62us at 34.5 TB/s). v6 stages
// candidates in 8KB double-buffered LDS chunks shared by the block's 4 waves
// (T14 async split: issue loads -> compute chunk -> LDS write -> barrier),
// cutting L2 reads 4x to ~0.5 GB. Values pass through LDS verbatim and j is
// processed in the same ascending order, so distances AND the selected top-16
// are bit-identical to v5. Insert machinery unchanged. Distances are batched
// 8-wide before the ballots (stale s15 only admits false survivors, which the
// dc < s15 recheck rejects; stability preserved: ascending s, ascending lane).
// ---------------------------------------------------------------------------
#define KCH 512                     // candidates per staged chunk (8 KB)
#define NCH (N_PTS / KCH)           // 16 chunks

__global__ __launch_bounds__(256) void knn_select_kernel(
    const float4* __restrict__ xyz4, int* __restrict__ nbr) {
  __shared__ float4 cs[2][KCH];     // 16 KB double-buffered candidate stage
  const int tid = threadIdx.x;
  const int lane = tid & 63;
  const int wave = tid >> 6;
  const int i = blockIdx.x * 4 + wave;

  const float4 pi = xyz4[i];
  const float xi = pi.x, yi = pi.y, zi = pi.z, sqi = pi.w;

  // ---- pass A: per-lane running min over staged chunks ----
  float4 p0 = xyz4[tid];
  float4 p1 = xyz4[tid + 256];
  cs[0][tid] = p0;
  cs[0][tid + 256] = p1;
  __syncthreads();

  float lmin0 = FLT_MAX, lmin1 = FLT_MAX;
  for (int c = 0; c < NCH; ++c) {
    const int b = c & 1;
    if (c < NCH - 1) {              // issue next-chunk loads early (T14)
      p0 = xyz4[(c + 1) * KCH + tid];
      p1 = xyz4[(c + 1) * KCH + tid + 256];
    }
    const int base = c * KCH;
    #pragma unroll
    for (int s = 0; s < 8; s += 2) {
      const float4 q0 = cs[b][s * 64 + lane];
      const float4 q1 = cs[b][(s + 1) * 64 + lane];
      lmin0 = fminf(lmin0, cand_dist(q0, xi, yi, zi, sqi,
                                     base + s * 64 + lane, i));
      lmin1 = fminf(lmin1, cand_dist(q1, xi, yi, zi, sqi,
                                     base + (s + 1) * 64 + lane, i));
    }
    if (c < NCH - 1) {              // LDS write late; HBM/L2 latency hidden
      cs[b ^ 1][tid] = p0;
      cs[b ^ 1][tid + 256] = p1;
    }
    __syncthreads();
  }
  const float lmin = fminf(lmin0, lmin1);

  // ---- 64-lane bitonic sort (ascending) of the lane-mins ----
  float v = lmin;
  #pragma unroll
  for (int k = 2; k <= 64; k <<= 1) {
    #pragma unroll
    for (int j = k >> 1; j > 0; j >>= 1) {
      const float o = __shfl_xor(v, j, 64);
      const bool up = ((lane & k) == 0);
      const bool lo = ((lane & j) == 0);
      v = (up == lo) ? fminf(v, o) : fmaxf(v, o);
    }
  }
  const float t = __shfl(v, 15, 64);   // >= true 16th-smallest distance

  // ---- pass B: re-stream from LDS; survivors hit the serial insert ----
  float sd = FLT_MAX;      // slot distance (lanes 0..15 meaningful)
  int sj = 0;              // slot index
  float s15 = FLT_MAX;     // current 16th-best (uniform)

  p0 = xyz4[tid];
  p1 = xyz4[tid + 256];
  cs[0][tid] = p0;
  cs[0][tid + 256] = p1;
  __syncthreads();

  for (int c = 0; c < NCH; ++c) {
    const int b = c & 1;
    if (c < NCH - 1) {
      p0 = xyz4[(c + 1) * KCH + tid];
      p1 = xyz4[(c + 1) * KCH + tid + 256];
    }
    const int cbase = c * KCH;

    float dd[8];
    #pragma unroll
    for (int s = 0; s < 8; ++s) {
      const float4 q = cs[b][s * 64 + lane];
      dd[s] = cand_dist(q, xi, yi, zi, sqi, cbase + s * 64 + lane, i);
    }

    #pragma unroll
    for (int s = 0; s < 8; ++s) {
      unsigned long long m = __ballot((dd[s] < s15) && (dd[s] <= t));
      const int base = cbase + s * 64;
      while (m) {                          // m is wave-uniform
        const int src = __ffsll(m) - 1;    // ascending lane == ascending j
        m &= m - 1;
        const float dc = __shfl(dd[s], src);
        if (dc < s15) {                    // recheck vs tightened bound
          const int jc = base + src;
          const unsigned long long bm = __ballot(sd <= dc) & 0xFFFFull;
          const int pos = (int)__popcll(bm);      // stable position
          const float pu = __shfl_up(sd, 1);
          const int ju = __shfl_up(sj, 1);
          if (lane < 16) {
            if (lane > pos)        { sd = pu; sj = ju; }
            else if (lane == pos)  { sd = dc; sj = jc; }
          }
          s15 = __shfl(sd, 15);
        }
      }
    }

    if (c < NCH - 1) {
      cs[b ^ 1][tid] = p0;
      cs[b ^ 1][tid + 256] = p1;
    }
    __syncthreads();
  }
  if (lane < 16) nbr[i * KNN + lane] = sj;
}

// ---------------------------------------------------------------------------
// W1 -> Bt (transposed, n-major) bf16 hi/lo (frozen).
// ---------------------------------------------------------------------------
__global__ __launch_bounds__(256) void convert_w_kernel(
    const float* __restrict__ W1, short* __restrict__ bhi,
    short* __restrict__ blo) {
  const int n = blockIdx.x;      // 0..511
  const int k = threadIdx.x;     // 0..255
  const float v = (n < 256) ? W1[k * DTOK + n]
                            : W1[(259 + k) * DTOK + (n - 256)];
  short h = f2bf(v);
  bhi[n * 256 + k] = h;
  blo[n * 256 + k] = f2bf(v - bf2f(h));
}

// ---------------------------------------------------------------------------
// pq GEMM v2 (frozen from R9).
// ---------------------------------------------------------------------------
__global__ __launch_bounds__(256, 2) void pq_gemm_fused_kernel(
    const float* __restrict__ A, const short* __restrict__ Bthi,
    const short* __restrict__ Btlo, const float* __restrict__ xyz,
    const float* __restrict__ W1, const float* __restrict__ b1,
    float* __restrict__ R, float* __restrict__ Q) {
  __shared__ short Ahi[64][32], Alo[64][32];    // 4K + 4K
  __shared__ short Bhi[128][32], Blo[128][32];  // 8K + 8K
  __shared__ float Qs[64][65];                  // 16.6K
  __shared__ float sx[64][3];
  __shared__ float swz[6][64];
  __shared__ float sb1[64];

  const int tid = threadIdx.x;
  const int lane = tid & 63;
  const int wave = tid >> 6;
  const int l15 = lane & 15;
  const int quad = lane >> 4;
  const int mh = wave & 1;
  const int qh = wave >> 1;
  const int m0 = blockIdx.x * 64;
  const int np0 = blockIdx.y * 64;

  if (tid < 64) {
    sx[tid][0] = xyz[(m0 + tid) * 3];
    sx[tid][1] = xyz[(m0 + tid) * 3 + 1];
    sx[tid][2] = xyz[(m0 + tid) * 3 + 2];
  } else if (tid < 128) {
    int n = tid - 64;
    sb1[n] = b1[np0 + n];
    #pragma unroll
    for (int r = 0; r < 3; ++r) {
      swz[r][n] = W1[(256 + r) * DTOK + np0 + n];
      swz[3 + r][n] = W1[(515 + r) * DTOK + np0 + n];
    }
  }

  float4v acc[2][4];
  #pragma unroll
  for (int mf = 0; mf < 2; ++mf)
    #pragma unroll
    for (int nf = 0; nf < 4; ++nf)
      #pragma unroll
      for (int e = 0; e < 4; ++e) acc[mf][nf][e] = 0.f;

  const int ar = tid >> 2;             // A staging row 0..63
  const int ak = (tid & 3) * 8;        // A staging k-offset

  #pragma unroll 1
  for (int kc = 0; kc < 8; ++kc) {
    const int k0 = kc * 32;
    __syncthreads();
    {
      const float* asrc = A + (size_t)(m0 + ar) * 256 + k0 + ak;
      float4 a0 = *(const float4*)asrc;
      float4 a1 = *(const float4*)(asrc + 4);
      float v[8] = {a0.x, a0.y, a0.z, a0.w, a1.x, a1.y, a1.z, a1.w};
      short8 h8, l8;
      #pragma unroll
      for (int e = 0; e < 8; ++e) {
        short h = f2bf(v[e]);
        h8[e] = h;
        l8[e] = f2bf(v[e] - bf2f(h));
      }
      *(short8*)(&Ahi[ar][ak]) = h8;
      *(short8*)(&Alo[ar][ak]) = l8;
    }
    #pragma unroll
    for (int l = 0; l < 4; ++l) {
      const int rem = tid + 256 * (l & 1);
      const int row = rem >> 2;
      const int koff = (rem & 3) * 8;
      const int n = (row < 64) ? (np0 + row) : (256 + np0 + row - 64);
      const short* src = ((l < 2) ? Bthi : Btlo) + (size_t)n * 256 + k0 + koff;
      short8 vv = *(const short8*)src;
      if (l < 2) *(short8*)(&Bhi[row][koff]) = vv;
      else       *(short8*)(&Blo[row][koff]) = vv;
    }
    __syncthreads();

    short8 ah[2], al[2], bh[4], bl[4];
    #pragma unroll
    for (int mf = 0; mf < 2; ++mf) {
      ah[mf] = *(const short8*)(&Ahi[mh * 32 + mf * 16 + l15][quad * 8]);
      al[mf] = *(const short8*)(&Alo[mh * 32 + mf * 16 + l15][quad * 8]);
    }
    #pragma unroll
    for (int nf = 0; nf < 4; ++nf) {
      bh[nf] = *(const short8*)(&Bhi[qh * 64 + nf * 16 + l15][quad * 8]);
      bl[nf] = *(const short8*)(&Blo[qh * 64 + nf * 16 + l15][quad * 8]);
    }
    #pragma unroll
    for (int mf = 0; mf < 2; ++mf)
      #pragma unroll
      for (int nf = 0; nf < 4; ++nf) {
        acc[mf][nf] = __builtin_amdgcn_mfma_f32_16x16x32_bf16(
            ah[mf], bh[nf], acc[mf][nf], 0, 0, 0);
        acc[mf][nf] = __builtin_amdgcn_mfma_f32_16x16x32_bf16(
            ah[mf], bl[nf], acc[mf][nf], 0, 0, 0);
        acc[mf][nf] = __builtin_amdgcn_mfma_f32_16x16x32_bf16(
            al[mf], bh[nf], acc[mf][nf], 0, 0, 0);
      }
  }

  if (qh == 1) {
    #pragma unroll
    for (int mf = 0; mf < 2; ++mf)
      #pragma unroll
      for (int nf = 0; nf < 4; ++nf)
        #pragma unroll
        for (int e = 0; e < 4; ++e) {
          int row = mh * 32 + mf * 16 + quad * 4 + e;
          int col = nf * 16 + l15;
          float q = acc[mf][nf][e] + sx[row][0] * swz[3][col] +
                    sx[row][1] * swz[4][col] + sx[row][2] * swz[5][col];
          Qs[row][col] = q;
          Q[(size_t)(m0 + row) * DTOK + np0 + col] = q;
        }
  }
  __syncthreads();
  if (qh == 0) {
    #pragma unroll
    for (int mf = 0; mf < 2; ++mf)
      #pragma unroll
      for (int nf = 0; nf < 4; ++nf)
        #pragma unroll
        for (int e = 0; e < 4; ++e) {
          int row = mh * 32 + mf * 16 + quad * 4 + e;
          int col = nf * 16 + l15;
          float p = acc[mf][nf][e] + sx[row][0] * swz[0][col] +
                    sx[row][1] * swz[1][col] + sx[row][2] * swz[2][col];
          R[(size_t)(m0 + row) * DTOK + np0 + col] =
              (p + sb1[col]) - Qs[row][col];
        }
  }
}

// ---------------------------------------------------------------------------
// EdgeConv via MFMA (EXACT R10 version -- R11's global-B variant regressed
// 68 -> ~110 us/launch; W2 register fragments restored).
// ---------------------------------------------------------------------------
#define EP 8          // points per group

__global__ __launch_bounds__(256, 2) void edge_mfma_kernel(
    const float* __restrict__ R, const float* __restrict__ Q,
    const int* __restrict__ nbr, const float* __restrict__ W2,
    const float* __restrict__ b2, float* __restrict__ out,
    int num_groups, int groups_per_block) {
  __shared__ short Hs[EP * KNN * DTOK];   // 128 rows x 256, 64 KB
  const int lane = threadIdx.x & 63;
  const int wave = threadIdx.x >> 6;
  const int l15 = lane & 15;
  const int quad = lane >> 4;

  short8 bfr[4][8];
  #pragma unroll
  for (int nt_i = 0; nt_i < 4; ++nt_i) {
    const int n = (wave * 4 + nt_i) * 16 + l15;
    #pragma unroll
    for (int kt = 0; kt < 8; ++kt) {
      short8 f;
      #pragma unroll
      for (int jj = 0; jj < 8; ++jj) {
        int k = kt * 32 + quad * 8 + jj;
        f[jj] = f2bf(W2[k * DTOK + n]);
      }
      bfr[nt_i][kt] = f;
    }
  }

  const int wc8 = lane >> 1;
  const int wsub = (lane & 1) * 4;

  for (int gi = 0; gi < groups_per_block; ++gi) {
    const int g = blockIdx.x + gi * gridDim.x;
    if (g >= num_groups) break;
    const int i0 = g * EP;

    // ---- build H: prefetched nbr via lane reg + shfl, pipelined gathers ----
    {
      const int ia = i0 + wave * 2;
      const int jr0 = nbr[ia * KNN + l15];
      const int jr1 = nbr[(ia + 1) * KNN + l15];
      const float4 ri0 = ((const float4*)(R + (size_t)ia * DTOK))[lane];
      const float4 ri1 = ((const float4*)(R + (size_t)(ia + 1) * DTOK))[lane];
      #pragma unroll
      for (int pp = 0; pp < 2; ++pp) {
        const float4 ri = pp ? ri1 : ri0;
        const int jr = pp ? jr1 : jr0;
        #pragma unroll
        for (int k = 0; k < KNN; ++k) {
          const int j = __shfl(jr, k, 16);
          const float4 qj = ((const float4*)(Q + (size_t)j * DTOK))[lane];
          const int r = wave * 32 + pp * 16 + k;
          uint2 pk;
          pk.x = ((unsigned)(unsigned short)f2bf(fmaxf(ri.x + qj.x, 0.f))) |
                 (((unsigned)(unsigned short)f2bf(fmaxf(ri.y + qj.y, 0.f))) << 16);
          pk.y = ((unsigned)(unsigned short)f2bf(fmaxf(ri.z + qj.z, 0.f))) |
                 (((unsigned)(unsigned short)f2bf(fmaxf(ri.w + qj.w, 0.f))) << 16);
          *(uint2*)(&Hs[r * DTOK + ((wc8 ^ (r & 7)) << 3) + wsub]) = pk;
        }
      }
    }
    __syncthreads();

    #pragma unroll
    for (int mp = 0; mp < 4; ++mp) {
      float4v acc[2][4];
      #pragma unroll
      for (int mi = 0; mi < 2; ++mi)
        #pragma unroll
        for (int nt_i = 0; nt_i < 4; ++nt_i)
          #pragma unroll
          for (int e = 0; e < 4; ++e) acc[mi][nt_i][e] = 0.f;

      #pragma unroll
      for (int kt = 0; kt < 8; ++kt) {
        const int pc = ((kt * 4 + quad) ^ (l15 & 7)) << 3;
        const short8 a0 = *(const short8*)(
            &Hs[((mp * 2 + 0) * 16 + l15) * DTOK + pc]);
        const short8 a1 = *(const short8*)(
            &Hs[((mp * 2 + 1) * 16 + l15) * DTOK + pc]);
        #pragma unroll
        for (int nt_i = 0; nt_i < 4; ++nt_i) {
          acc[0][nt_i] = __builtin_amdgcn_mfma_f32_16x16x32_bf16(
              a0, bfr[nt_i][kt], acc[0][nt_i], 0, 0, 0);
          acc[1][nt_i] = __builtin_amdgcn_mfma_f32_16x16x32_bf16(
              a1, bfr[nt_i][kt], acc[1][nt_i], 0, 0, 0);
        }
      }

      #pragma unroll
      for (int mi = 0; mi < 2; ++mi) {
        #pragma unroll
        for (int nt_i = 0; nt_i < 4; ++nt_i) {
          float rm = fmaxf(fmaxf(acc[mi][nt_i][0], acc[mi][nt_i][1]),
                           fmaxf(acc[mi][nt_i][2], acc[mi][nt_i][3]));
          rm = fmaxf(rm, __shfl_xor(rm, 16, 64));
          rm = fmaxf(rm, __shfl_xor(rm, 32, 64));
          if (lane < 16) {
            const int i = i0 + mp * 2 + mi;
            const int n = (wave * 4 + nt_i) * 16 + lane;
            out[(size_t)i * DTOK + n] = rm + b2[n];
          }
        }
      }
    }
    __syncthreads();
  }
}

// ---------------------------------------------------------------------------
extern "C" void kernel_launch(void* const* d_in, const int* in_sizes, int n_in,
                              void* d_out, int out_size, void* d_ws,
                              size_t ws_size, hipStream_t stream) {
  const float* xyz = (const float*)d_in[0];
  const float* feat = (const float*)d_in[1];
  const float* W1a = (const float*)d_in[2];
  const float* b1a = (const float*)d_in[3];
  const float* W2a = (const float*)d_in[4];
  const float* b2a = (const float*)d_in[5];
  const float* W1b = (const float*)d_in[6];
  const float* b1b = (const float*)d_in[7];
  const float* W2b = (const float*)d_in[8];
  const float* b2b = (const float*)d_in[9];
  float* out = (float*)d_out;

  // ws layout (~25 MB): nbr 0.5 | xyz4 128KB (then R at +8MB) | Q | Bt hi/lo
  char* w = (char*)d_ws;
  const size_t SZ_NBR = (size_t)N_PTS * KNN * sizeof(int);        // 512 KB
  const size_t MB = 1024 * 1024;
  int* nbr = (int*)w;
  char* w1 = w + SZ_NBR;
  float4* xyz4 = (float4*)w1;                  // 128 KB
  float* R = (float*)(w1 + 8 * MB);            // 8 MB
  float* Q = (float*)(w + SZ_NBR + 16 * MB);   // 8 MB
  short* Bthi = (short*)(w + SZ_NBR + 24 * MB);// 256 KB
  short* Btlo = Bthi + 512 * 256;              // 256 KB
  float* bufC = out;                           // layer-a output staging

  knn_prep_kernel<<<N_PTS / 256, 256, 0, stream>>>(xyz, xyz4);
  knn_select_kernel<<<N_PTS / 4, 256, 0, stream>>>(xyz4, nbr);

  const int num_groups = N_PTS / EP;           // 1024
  const int nblocks = 512;

  // layer a
  convert_w_kernel<<<512, 256, 0, stream>>>(W1a, Bthi, Btlo);
  pq_gemm_fused_kernel<<<dim3(N_PTS / 64, 4), 256, 0, stream>>>(
      feat, Bthi, Btlo, xyz, W1a, b1a, R, Q);
  edge_mfma_kernel<<<nblocks, 256, 0, stream>>>(R, Q, nbr, W2a, b2a, bufC,
                                                num_groups, 2);

  // layer b
  convert_w_kernel<<<512, 256, 0, stream>>>(W1b, Bthi, Btlo);
  pq_gemm_fused_kernel<<<dim3(N_PTS / 64, 4), 256, 0, stream>>>(
      bufC, Bthi, Btlo, xyz, W1b, b1b, R, Q);
  edge_mfma_kernel<<<nblocks, 256, 0, stream>>>(R, Q, nbr, W2b, b2b, out,
                                                num_groups, 2);
}

// Round 3
// 239.689 us; speedup vs baseline: 1.1159x; 1.0019x over previous
//
#include <hip/hip_runtime.h>
#include <cfloat>

#define N_PTS 8192
#define DTOK 256
#define KNN 16

typedef __attribute__((ext_vector_type(8))) short short8;
typedef __attribute__((ext_vector_type(4))) float float4v;
typedef __attribute__((ext_vector_type(2))) float float2v;

__device__ inline short f2bf(float f) {   // RTNE fp32 -> bf16
  unsigned u = __float_as_uint(f);
  u += 0x7fffu + ((u >> 16) & 1u);
  return (short)(u >> 16);
}
__device__ inline float bf2f(short h) {
  return __uint_as_float(((unsigned)(unsigned short)h) << 16);
}

// ---- VOP3P packed fp32 helpers: 2 IEEE-RN fp32 ops per issue slot --------
__device__ inline float2v pk_mul(float2v a, float2v b) {
  float2v d;
  asm("v_pk_mul_f32 %0, %1, %2" : "=v"(d) : "v"(a), "v"(b));
  return d;
}
__device__ inline float2v pk_fma(float2v a, float2v b, float2v c) {
  float2v d;
  asm("v_pk_fma_f32 %0, %1, %2, %3" : "=v"(d) : "v"(a), "v"(b), "v"(c));
  return d;
}
__device__ inline float2v pk_add(float2v a, float2v b) {
  float2v d;
  asm("v_pk_add_f32 %0, %1, %2" : "=v"(d) : "v"(a), "v"(b));
  return d;
}
__device__ inline float2v pk_sub(float2v a, float2v b) {   // a - b (RN)
  float2v d;
  asm("v_pk_add_f32 %0, %1, %2 neg_lo:[0,1] neg_hi:[0,1]"
      : "=v"(d) : "v"(a), "v"(b));
  return d;
}

// ---------------------------------------------------------------------------
// Pack xyz -> (x,y,z,sq) with the exact rounding the old knn used, so all
// distances (and thus KNN indices) are bit-identical.
// ---------------------------------------------------------------------------
__global__ __launch_bounds__(256) void knn_prep_kernel(
    const float* __restrict__ xyz, float4* __restrict__ xyz4) {
  const int i = blockIdx.x * 256 + threadIdx.x;
  float x = xyz[3 * i], y = xyz[3 * i + 1], z = xyz[3 * i + 2];
  float sq = __fadd_rn(__fadd_rn(__fmul_rn(x, x), __fmul_rn(y, y)),
                       __fmul_rn(z, z));
  xyz4[i] = make_float4(x, y, z, sq);
}

// ---------------------------------------------------------------------------
// KNN v7: v6 (two-pass threshold + LDS chunk sharing) + packed-fp32 distance
// math. R2 post-mortem: VALU-issue-bound (VALUBusy 75%, 42us of VALU issue).
// v7 halves the per-candidate issue count:
//  - v_pk_{mul,fma,add}_f32 compute 2 candidates per instruction with the
//    EXACT same IEEE-RN rounding sequence (mul, fma, fma, mul2, sub, add) ->
//    distances bit-identical.
//  - LDS staged as pair-SoA: sA[ps][lane]={x0,x1,y0,y1}, sB={z0,z1,w0,w1}
//    (pair = candidates j0=cbase+ps*128+lane, j1=j0+64). Staging thread owns
//    both halves so writes stay ds_write_b128; reads stay ds_read_b128 and
//    float2 subvectors feed pk ops with no repack movs.
//  - self-candidate (j==i) fix hoisted to a wave-uniform branch (the 128-
//    group containing i is uniform) -- removes per-candidate cmp+cndmask.
//  - pass-B ballot predicate is just (d <= t); the dc < s15 recheck inside
//    the insert rejects stale survivors. Processing order (ascending j)
//    and insert machinery unchanged -> top-16 bit-identical.
// ---------------------------------------------------------------------------
#define KCH 512                     // candidates per staged chunk
#define NCH (N_PTS / KCH)           // 16 chunks

__global__ __launch_bounds__(256) void knn_select_kernel(
    const float4* __restrict__ xyz4, int* __restrict__ nbr) {
  __shared__ float4 sA[2][4][64];   // {x0,x1,y0,y1} per pair, 8 KB
  __shared__ float4 sB[2][4][64];   // {z0,z1,w0,w1} per pair, 8 KB
  const int tid = threadIdx.x;
  const int lane = tid & 63;
  const int wave = tid >> 6;
  const int i = blockIdx.x * 4 + wave;

  const float4 pi = xyz4[i];
  const float2v xi2 = {pi.x, pi.x};
  const float2v yi2 = {pi.y, pi.y};
  const float2v zi2 = {pi.z, pi.z};
  const float2v sqi2 = {pi.w, pi.w};
  const float2v two2 = {2.0f, 2.0f};

  const int ib128 = i & ~127;       // uniform: 128-block containing i
  const int ihalf = (i >> 6) & 1;   // uniform
  const int il = i & 63;            // uniform

  // staging coords: wave w stages pair-group ps=w of each chunk
  const int sgj = wave * 128 + lane;

  // ---- prologue: stage chunk 0 ----
  {
    const float4 q0 = xyz4[sgj];
    const float4 q1 = xyz4[sgj + 64];
    sA[0][wave][lane] = make_float4(q0.x, q1.x, q0.y, q1.y);
    sB[0][wave][lane] = make_float4(q0.z, q1.z, q0.w, q1.w);
  }
  __syncthreads();

  // ---- pass A: per-lane running min over staged chunks ----
  float lmin0 = FLT_MAX, lmin1 = FLT_MAX;
  for (int c = 0; c < NCH; ++c) {
    const int b = c & 1;
    float4 n0, n1;
    if (c < NCH - 1) {              // issue next-chunk loads early (T14)
      n0 = xyz4[(c + 1) * KCH + sgj];
      n1 = xyz4[(c + 1) * KCH + sgj + 64];
    }
    const int cbase = c * KCH;
    #pragma unroll
    for (int ps = 0; ps < 4; ++ps) {
      const float4 a = sA[b][ps][lane];
      const float4 bb = sB[b][ps][lane];
      const float2v px = {a.x, a.y}, py = {a.z, a.w};
      const float2v pz = {bb.x, bb.y}, pw = {bb.z, bb.w};
      const float2v dot = pk_fma(zi2, pz, pk_fma(yi2, py, pk_mul(xi2, px)));
      float2v d = pk_add(pk_sub(sqi2, pk_mul(two2, dot)), pw);
      if (cbase + ps * 128 == ib128) {      // uniform rare branch
        if (lane == il) {
          if (ihalf) d.y = __fadd_rn(d.y, 1e10f);
          else       d.x = __fadd_rn(d.x, 1e10f);
        }
      }
      lmin0 = fminf(lmin0, d.x);
      lmin1 = fminf(lmin1, d.y);
    }
    if (c < NCH - 1) {              // LDS write late; latency hidden
      sA[b ^ 1][wave][lane] = make_float4(n0.x, n1.x, n0.y, n1.y);
      sB[b ^ 1][wave][lane] = make_float4(n0.z, n1.z, n0.w, n1.w);
    }
    __syncthreads();
  }
  const float lmin = fminf(lmin0, lmin1);

  // ---- 64-lane bitonic sort (ascending) of the lane-mins ----
  float v = lmin;
  #pragma unroll
  for (int k = 2; k <= 64; k <<= 1) {
    #pragma unroll
    for (int j = k >> 1; j > 0; j >>= 1) {
      const float o = __shfl_xor(v, j, 64);
      const bool up = ((lane & k) == 0);
      const bool lo = ((lane & j) == 0);
      v = (up == lo) ? fminf(v, o) : fmaxf(v, o);
    }
  }
  const float t = __shfl(v, 15, 64);   // >= true 16th-smallest distance

  // ---- pass B: re-stream from LDS; survivors hit the serial insert ----
  float sd = FLT_MAX;      // slot distance (lanes 0..15 meaningful)
  int sj = 0;              // slot index
  float s15 = FLT_MAX;     // current 16th-best (uniform)

  {
    const float4 q0 = xyz4[sgj];
    const float4 q1 = xyz4[sgj + 64];
    sA[0][wave][lane] = make_float4(q0.x, q1.x, q0.y, q1.y);
    sB[0][wave][lane] = make_float4(q0.z, q1.z, q0.w, q1.w);
  }
  __syncthreads();

  for (int c = 0; c < NCH; ++c) {
    const int b = c & 1;
    float4 n0, n1;
    if (c < NCH - 1) {
      n0 = xyz4[(c + 1) * KCH + sgj];
      n1 = xyz4[(c + 1) * KCH + sgj + 64];
    }
    const int cbase = c * KCH;

    float2v dd[4];
    #pragma unroll
    for (int ps = 0; ps < 4; ++ps) {
      const float4 a = sA[b][ps][lane];
      const float4 bb = sB[b][ps][lane];
      const float2v px = {a.x, a.y}, py = {a.z, a.w};
      const float2v pz = {bb.x, bb.y}, pw = {bb.z, bb.w};
      const float2v dot = pk_fma(zi2, pz, pk_fma(yi2, py, pk_mul(xi2, px)));
      dd[ps] = pk_add(pk_sub(sqi2, pk_mul(two2, dot)), pw);
      if (cbase + ps * 128 == ib128) {      // uniform rare branch
        if (lane == il) {
          if (ihalf) dd[ps].y = __fadd_rn(dd[ps].y, 1e10f);
          else       dd[ps].x = __fadd_rn(dd[ps].x, 1e10f);
        }
      }
    }

    #pragma unroll
    for (int ps = 0; ps < 4; ++ps) {
      #pragma unroll
      for (int h = 0; h < 2; ++h) {
        const float d = h ? dd[ps].y : dd[ps].x;
        const int base = cbase + ps * 128 + h * 64;
        unsigned long long m = __ballot(d <= t);
        while (m) {                          // m is wave-uniform
          const int src = __ffsll(m) - 1;    // ascending lane == ascending j
          m &= m - 1;
          const float dc = __shfl(d, src);
          if (dc < s15) {                    // recheck vs running bound
            const int jc = base + src;
            const unsigned long long bm = __ballot(sd <= dc) & 0xFFFFull;
            const int pos = (int)__popcll(bm);      // stable position
            const float pu = __shfl_up(sd, 1);
            const int ju = __shfl_up(sj, 1);
            if (lane < 16) {
              if (lane > pos)        { sd = pu; sj = ju; }
              else if (lane == pos)  { sd = dc; sj = jc; }
            }
            s15 = __shfl(sd, 15);
          }
        }
      }
    }

    if (c < NCH - 1) {
      sA[b ^ 1][wave][lane] = make_float4(n0.x, n1.x, n0.y, n1.y);
      sB[b ^ 1][wave][lane] = make_float4(n0.z, n1.z, n0.w, n1.w);
    }
    __syncthreads();
  }
  if (lane < 16) nbr[i * KNN + lane] = sj;
}

// ---------------------------------------------------------------------------
// W1 -> Bt (transposed, n-major) bf16 hi/lo (frozen).
// ---------------------------------------------------------------------------
__global__ __launch_bounds__(256) void convert_w_kernel(
    const float* __restrict__ W1, short* __restrict__ bhi,
    short* __restrict__ blo) {
  const int n = blockIdx.x;      // 0..511
  const int k = threadIdx.x;     // 0..255
  const float v = (n < 256) ? W1[k * DTOK + n]
                            : W1[(259 + k) * DTOK + (n - 256)];
  short h = f2bf(v);
  bhi[n * 256 + k] = h;
  blo[n * 256 + k] = f2bf(v - bf2f(h));
}

// ---------------------------------------------------------------------------
// pq GEMM v2 (frozen from R9).
// ---------------------------------------------------------------------------
__global__ __launch_bounds__(256, 2) void pq_gemm_fused_kernel(
    const float* __restrict__ A, const short* __restrict__ Bthi,
    const short* __restrict__ Btlo, const float* __restrict__ xyz,
    const float* __restrict__ W1, const float* __restrict__ b1,
    float* __restrict__ R, float* __restrict__ Q) {
  __shared__ short Ahi[64][32], Alo[64][32];    // 4K + 4K
  __shared__ short Bhi[128][32], Blo[128][32];  // 8K + 8K
  __shared__ float Qs[64][65];                  // 16.6K
  __shared__ float sx[64][3];
  __shared__ float swz[6][64];
  __shared__ float sb1[64];

  const int tid = threadIdx.x;
  const int lane = tid & 63;
  const int wave = tid >> 6;
  const int l15 = lane & 15;
  const int quad = lane >> 4;
  const int mh = wave & 1;
  const int qh = wave >> 1;
  const int m0 = blockIdx.x * 64;
  const int np0 = blockIdx.y * 64;

  if (tid < 64) {
    sx[tid][0] = xyz[(m0 + tid) * 3];
    sx[tid][1] = xyz[(m0 + tid) * 3 + 1];
    sx[tid][2] = xyz[(m0 + tid) * 3 + 2];
  } else if (tid < 128) {
    int n = tid - 64;
    sb1[n] = b1[np0 + n];
    #pragma unroll
    for (int r = 0; r < 3; ++r) {
      swz[r][n] = W1[(256 + r) * DTOK + np0 + n];
      swz[3 + r][n] = W1[(515 + r) * DTOK + np0 + n];
    }
  }

  float4v acc[2][4];
  #pragma unroll
  for (int mf = 0; mf < 2; ++mf)
    #pragma unroll
    for (int nf = 0; nf < 4; ++nf)
      #pragma unroll
      for (int e = 0; e < 4; ++e) acc[mf][nf][e] = 0.f;

  const int ar = tid >> 2;             // A staging row 0..63
  const int ak = (tid & 3) * 8;        // A staging k-offset

  #pragma unroll 1
  for (int kc = 0; kc < 8; ++kc) {
    const int k0 = kc * 32;
    __syncthreads();
    {
      const float* asrc = A + (size_t)(m0 + ar) * 256 + k0 + ak;
      float4 a0 = *(const float4*)asrc;
      float4 a1 = *(const float4*)(asrc + 4);
      float v[8] = {a0.x, a0.y, a0.z, a0.w, a1.x, a1.y, a1.z, a1.w};
      short8 h8, l8;
      #pragma unroll
      for (int e = 0; e < 8; ++e) {
        short h = f2bf(v[e]);
        h8[e] = h;
        l8[e] = f2bf(v[e] - bf2f(h));
      }
      *(short8*)(&Ahi[ar][ak]) = h8;
      *(short8*)(&Alo[ar][ak]) = l8;
    }
    #pragma unroll
    for (int l = 0; l < 4; ++l) {
      const int rem = tid + 256 * (l & 1);
      const int row = rem >> 2;
      const int koff = (rem & 3) * 8;
      const int n = (row < 64) ? (np0 + row) : (256 + np0 + row - 64);
      const short* src = ((l < 2) ? Bthi : Btlo) + (size_t)n * 256 + k0 + koff;
      short8 vv = *(const short8*)src;
      if (l < 2) *(short8*)(&Bhi[row][koff]) = vv;
      else       *(short8*)(&Blo[row][koff]) = vv;
    }
    __syncthreads();

    short8 ah[2], al[2], bh[4], bl[4];
    #pragma unroll
    for (int mf = 0; mf < 2; ++mf) {
      ah[mf] = *(const short8*)(&Ahi[mh * 32 + mf * 16 + l15][quad * 8]);
      al[mf] = *(const short8*)(&Alo[mh * 32 + mf * 16 + l15][quad * 8]);
    }
    #pragma unroll
    for (int nf = 0; nf < 4; ++nf) {
      bh[nf] = *(const short8*)(&Bhi[qh * 64 + nf * 16 + l15][quad * 8]);
      bl[nf] = *(const short8*)(&Blo[qh * 64 + nf * 16 + l15][quad * 8]);
    }
    #pragma unroll
    for (int mf = 0; mf < 2; ++mf)
      #pragma unroll
      for (int nf = 0; nf < 4; ++nf) {
        acc[mf][nf] = __builtin_amdgcn_mfma_f32_16x16x32_bf16(
            ah[mf], bh[nf], acc[mf][nf], 0, 0, 0);
        acc[mf][nf] = __builtin_amdgcn_mfma_f32_16x16x32_bf16(
            ah[mf], bl[nf], acc[mf][nf], 0, 0, 0);
        acc[mf][nf] = __builtin_amdgcn_mfma_f32_16x16x32_bf16(
            al[mf], bh[nf], acc[mf][nf], 0, 0, 0);
      }
  }

  if (qh == 1) {
    #pragma unroll
    for (int mf = 0; mf < 2; ++mf)
      #pragma unroll
      for (int nf = 0; nf < 4; ++nf)
        #pragma unroll
        for (int e = 0; e < 4; ++e) {
          int row = mh * 32 + mf * 16 + quad * 4 + e;
          int col = nf * 16 + l15;
          float q = acc[mf][nf][e] + sx[row][0] * swz[3][col] +
                    sx[row][1] * swz[4][col] + sx[row][2] * swz[5][col];
          Qs[row][col] = q;
          Q[(size_t)(m0 + row) * DTOK + np0 + col] = q;
        }
  }
  __syncthreads();
  if (qh == 0) {
    #pragma unroll
    for (int mf = 0; mf < 2; ++mf)
      #pragma unroll
      for (int nf = 0; nf < 4; ++nf)
        #pragma unroll
        for (int e = 0; e < 4; ++e) {
          int row = mh * 32 + mf * 16 + quad * 4 + e;
          int col = nf * 16 + l15;
          float p = acc[mf][nf][e] + sx[row][0] * swz[0][col] +
                    sx[row][1] * swz[1][col] + sx[row][2] * swz[2][col];
          R[(size_t)(m0 + row) * DTOK + np0 + col] =
              (p + sb1[col]) - Qs[row][col];
        }
  }
}

// ---------------------------------------------------------------------------
// EdgeConv via MFMA (EXACT R10 version -- R11's global-B variant regressed
// 68 -> ~110 us/launch; W2 register fragments restored).
// ---------------------------------------------------------------------------
#define EP 8          // points per group

__global__ __launch_bounds__(256, 2) void edge_mfma_kernel(
    const float* __restrict__ R, const float* __restrict__ Q,
    const int* __restrict__ nbr, const float* __restrict__ W2,
    const float* __restrict__ b2, float* __restrict__ out,
    int num_groups, int groups_per_block) {
  __shared__ short Hs[EP * KNN * DTOK];   // 128 rows x 256, 64 KB
  const int lane = threadIdx.x & 63;
  const int wave = threadIdx.x >> 6;
  const int l15 = lane & 15;
  const int quad = lane >> 4;

  short8 bfr[4][8];
  #pragma unroll
  for (int nt_i = 0; nt_i < 4; ++nt_i) {
    const int n = (wave * 4 + nt_i) * 16 + l15;
    #pragma unroll
    for (int kt = 0; kt < 8; ++kt) {
      short8 f;
      #pragma unroll
      for (int jj = 0; jj < 8; ++jj) {
        int k = kt * 32 + quad * 8 + jj;
        f[jj] = f2bf(W2[k * DTOK + n]);
      }
      bfr[nt_i][kt] = f;
    }
  }

  const int wc8 = lane >> 1;
  const int wsub = (lane & 1) * 4;

  for (int gi = 0; gi < groups_per_block; ++gi) {
    const int g = blockIdx.x + gi * gridDim.x;
    if (g >= num_groups) break;
    const int i0 = g * EP;

    // ---- build H: prefetched nbr via lane reg + shfl, pipelined gathers ----
    {
      const int ia = i0 + wave * 2;
      const int jr0 = nbr[ia * KNN + l15];
      const int jr1 = nbr[(ia + 1) * KNN + l15];
      const float4 ri0 = ((const float4*)(R + (size_t)ia * DTOK))[lane];
      const float4 ri1 = ((const float4*)(R + (size_t)(ia + 1) * DTOK))[lane];
      #pragma unroll
      for (int pp = 0; pp < 2; ++pp) {
        const float4 ri = pp ? ri1 : ri0;
        const int jr = pp ? jr1 : jr0;
        #pragma unroll
        for (int k = 0; k < KNN; ++k) {
          const int j = __shfl(jr, k, 16);
          const float4 qj = ((const float4*)(Q + (size_t)j * DTOK))[lane];
          const int r = wave * 32 + pp * 16 + k;
          uint2 pk;
          pk.x = ((unsigned)(unsigned short)f2bf(fmaxf(ri.x + qj.x, 0.f))) |
                 (((unsigned)(unsigned short)f2bf(fmaxf(ri.y + qj.y, 0.f))) << 16);
          pk.y = ((unsigned)(unsigned short)f2bf(fmaxf(ri.z + qj.z, 0.f))) |
                 (((unsigned)(unsigned short)f2bf(fmaxf(ri.w + qj.w, 0.f))) << 16);
          *(uint2*)(&Hs[r * DTOK + ((wc8 ^ (r & 7)) << 3) + wsub]) = pk;
        }
      }
    }
    __syncthreads();

    #pragma unroll
    for (int mp = 0; mp < 4; ++mp) {
      float4v acc[2][4];
      #pragma unroll
      for (int mi = 0; mi < 2; ++mi)
        #pragma unroll
        for (int nt_i = 0; nt_i < 4; ++nt_i)
          #pragma unroll
          for (int e = 0; e < 4; ++e) acc[mi][nt_i][e] = 0.f;

      #pragma unroll
      for (int kt = 0; kt < 8; ++kt) {
        const int pc = ((kt * 4 + quad) ^ (l15 & 7)) << 3;
        const short8 a0 = *(const short8*)(
            &Hs[((mp * 2 + 0) * 16 + l15) * DTOK + pc]);
        const short8 a1 = *(const short8*)(
            &Hs[((mp * 2 + 1) * 16 + l15) * DTOK + pc]);
        #pragma unroll
        for (int nt_i = 0; nt_i < 4; ++nt_i) {
          acc[0][nt_i] = __builtin_amdgcn_mfma_f32_16x16x32_bf16(
              a0, bfr[nt_i][kt], acc[0][nt_i], 0, 0, 0);
          acc[1][nt_i] = __builtin_amdgcn_mfma_f32_16x16x32_bf16(
              a1, bfr[nt_i][kt], acc[1][nt_i], 0, 0, 0);
        }
      }

      #pragma unroll
      for (int mi = 0; mi < 2; ++mi) {
        #pragma unroll
        for (int nt_i = 0; nt_i < 4; ++nt_i) {
          float rm = fmaxf(fmaxf(acc[mi][nt_i][0], acc[mi][nt_i][1]),
                           fmaxf(acc[mi][nt_i][2], acc[mi][nt_i][3]));
          rm = fmaxf(rm, __shfl_xor(rm, 16, 64));
          rm = fmaxf(rm, __shfl_xor(rm, 32, 64));
          if (lane < 16) {
            const int i = i0 + mp * 2 + mi;
            const int n = (wave * 4 + nt_i) * 16 + lane;
            out[(size_t)i * DTOK + n] = rm + b2[n];
          }
        }
      }
    }
    __syncthreads();
  }
}

// ---------------------------------------------------------------------------
extern "C" void kernel_launch(void* const* d_in, const int* in_sizes, int n_in,
                              void* d_out, int out_size, void* d_ws,
                              size_t ws_size, hipStream_t stream) {
  const float* xyz = (const float*)d_in[0];
  const float* feat = (const float*)d_in[1];
  const float* W1a = (const float*)d_in[2];
  const float* b1a = (const float*)d_in[3];
  const float* W2a = (const float*)d_in[4];
  const float* b2a = (const float*)d_in[5];
  const float* W1b = (const float*)d_in[6];
  const float* b1b = (const float*)d_in[7];
  const float* W2b = (const float*)d_in[8];
  const float* b2b = (const float*)d_in[9];
  float* out = (float*)d_out;

  // ws layout (~25 MB): nbr 0.5 | xyz4 128KB (then R at +8MB) | Q | Bt hi/lo
  char* w = (char*)d_ws;
  const size_t SZ_NBR = (size_t)N_PTS * KNN * sizeof(int);        // 512 KB
  const size_t MB = 1024 * 1024;
  int* nbr = (int*)w;
  char* w1 = w + SZ_NBR;
  float4* xyz4 = (float4*)w1;                  // 128 KB
  float* R = (float*)(w1 + 8 * MB);            // 8 MB
  float* Q = (float*)(w + SZ_NBR + 16 * MB);   // 8 MB
  short* Bthi = (short*)(w + SZ_NBR + 24 * MB);// 256 KB
  short* Btlo = Bthi + 512 * 256;              // 256 KB
  float* bufC = out;                           // layer-a output staging

  knn_prep_kernel<<<N_PTS / 256, 256, 0, stream>>>(xyz, xyz4);
  knn_select_kernel<<<N_PTS / 4, 256, 0, stream>>>(xyz4, nbr);

  const int num_groups = N_PTS / EP;           // 1024
  const int nblocks = 512;

  // layer a
  convert_w_kernel<<<512, 256, 0, stream>>>(W1a, Bthi, Btlo);
  pq_gemm_fused_kernel<<<dim3(N_PTS / 64, 4), 256, 0, stream>>>(
      feat, Bthi, Btlo, xyz, W1a, b1a, R, Q);
  edge_mfma_kernel<<<nblocks, 256, 0, stream>>>(R, Q, nbr, W2a, b2a, bufC,
                                                num_groups, 2);

  // layer b
  convert_w_kernel<<<512, 256, 0, stream>>>(W1b, Bthi, Btlo);
  pq_gemm_fused_kernel<<<dim3(N_PTS / 64, 4), 256, 0, stream>>>(
      bufC, Bthi, Btlo, xyz, W1b, b1b, R, Q);
  edge_mfma_kernel<<<nblocks, 256, 0, stream>>>(R, Q, nbr, W2b, b2b, out,
                                                num_groups, 2);
}

// Round 4
// 236.794 us; speedup vs baseline: 1.1296x; 1.0122x over previous
//
#include <hip/hip_runtime.h>
#include <cfloat>

#define N_PTS 8192
#define DTOK 256
#define KNN 16

typedef __attribute__((ext_vector_type(8))) short short8;
typedef __attribute__((ext_vector_type(4))) float float4v;
typedef __attribute__((ext_vector_type(2))) float float2v;

__device__ inline short f2bf(float f) {   // RTNE fp32 -> bf16
  unsigned u = __float_as_uint(f);
  u += 0x7fffu + ((u >> 16) & 1u);
  return (short)(u >> 16);
}
__device__ inline float bf2f(short h) {
  return __uint_as_float(((unsigned)(unsigned short)h) << 16);
}

// ---- VOP3P packed fp32 helpers: 2 IEEE-RN fp32 ops per issue slot --------
__device__ inline float2v pk_mul(float2v a, float2v b) {
  float2v d;
  asm("v_pk_mul_f32 %0, %1, %2" : "=v"(d) : "v"(a), "v"(b));
  return d;
}
__device__ inline float2v pk_fma(float2v a, float2v b, float2v c) {
  float2v d;
  asm("v_pk_fma_f32 %0, %1, %2, %3" : "=v"(d) : "v"(a), "v"(b), "v"(c));
  return d;
}
__device__ inline float2v pk_add(float2v a, float2v b) {
  float2v d;
  asm("v_pk_add_f32 %0, %1, %2" : "=v"(d) : "v"(a), "v"(b));
  return d;
}
__device__ inline float2v pk_sub(float2v a, float2v b) {   // a - b (RN)
  float2v d;
  asm("v_pk_add_f32 %0, %1, %2 neg_lo:[0,1] neg_hi:[0,1]"
      : "=v"(d) : "v"(a), "v"(b));
  return d;
}

// ---------------------------------------------------------------------------
// Pack xyz -> (x,y,z,sq) with the exact rounding the old knn used, so all
// distances (and thus KNN indices) are bit-identical.
// ---------------------------------------------------------------------------
__global__ __launch_bounds__(256) void knn_prep_kernel(
    const float* __restrict__ xyz, float4* __restrict__ xyz4) {
  const int i = blockIdx.x * 256 + threadIdx.x;
  float x = xyz[3 * i], y = xyz[3 * i + 1], z = xyz[3 * i + 2];
  float sq = __fadd_rn(__fadd_rn(__fmul_rn(x, x), __fmul_rn(y, y)),
                       __fmul_rn(z, z));
  xyz4[i] = make_float4(x, y, z, sq);
}

// Serial stable top-16 insert for one 64-candidate group (unchanged from v5).
__device__ inline void insert_group(float d, int base, float t, int lane,
                                    float& sd, int& sj, float& s15) {
  unsigned long long m = __ballot(d <= t);
  while (m) {                          // m is wave-uniform
    const int src = __ffsll(m) - 1;    // ascending lane == ascending j
    m &= m - 1;
    const float dc = __shfl(d, src);
    if (dc < s15) {                    // recheck vs running bound
      const int jc = base + src;
      const unsigned long long bm = __ballot(sd <= dc) & 0xFFFFull;
      const int pos = (int)__popcll(bm);      // stable position
      const float pu = __shfl_up(sd, 1);
      const int ju = __shfl_up(sj, 1);
      if (lane < 16) {
        if (lane > pos)        { sd = pu; sj = ju; }
        else if (lane == pos)  { sd = dc; sj = jc; }
      }
      s15 = __shfl(sd, 15);
    }
  }
}

// ---------------------------------------------------------------------------
// KNN v8: v7 + TWO QUERY POINTS PER WAVE.
// R3 post-mortem: LDS-READ-PIPE-bound, not VALU -- each wave pulls the full
// 128KB candidate set through the LDS read port per pass (256 ds_read_b128 x
// ~12cyc x 2 passes ~= 4.2k cyc/wave x 32 waves/CU ~= 55us, matching meas.).
// v8: each wave owns queries i0,i1 -- every candidate pair read ONCE feeds
// both queries' pk distance math. LDS reads per POINT halve (256->128 KB);
// VALU per point unchanged; pipes land balanced (~31us each, overlapped).
// Block = 4 waves = 8 points, grid 1024. Two interleaved bitonic sorts (ILP);
// independent top-16 states per query; per-query candidate order (ascending
// j) and every rounding step unchanged -> selected indices bit-identical.
// ---------------------------------------------------------------------------
#define KCH 512                     // candidates per staged chunk
#define NCH (N_PTS / KCH)           // 16 chunks

__global__ __launch_bounds__(256) void knn_select_kernel(
    const float4* __restrict__ xyz4, int* __restrict__ nbr) {
  __shared__ float4 sA[2][4][64];   // {x0,x1,y0,y1} per pair, 8 KB
  __shared__ float4 sB[2][4][64];   // {z0,z1,w0,w1} per pair, 8 KB
  const int tid = threadIdx.x;
  const int lane = tid & 63;
  const int wave = tid >> 6;
  const int i0 = blockIdx.x * 8 + wave * 2;
  const int i1 = i0 + 1;

  const float4 q0 = xyz4[i0];
  const float4 q1 = xyz4[i1];
  const float2v x02 = {q0.x, q0.x}, y02 = {q0.y, q0.y};
  const float2v z02 = {q0.z, q0.z}, s02 = {q0.w, q0.w};
  const float2v x12 = {q1.x, q1.x}, y12 = {q1.y, q1.y};
  const float2v z12 = {q1.z, q1.z}, s12 = {q1.w, q1.w};
  const float2v two2 = {2.0f, 2.0f};

  const int ib128 = i0 & ~127;      // uniform: shared 128-block of i0,i1
  const int ih0 = (i0 >> 6) & 1, il0 = i0 & 63;   // uniform
  const int ih1 = (i1 >> 6) & 1, il1 = i1 & 63;   // uniform

  // staging coords: wave w stages pair-group ps=w of each chunk
  const int sgj = wave * 128 + lane;

  // ---- prologue: stage chunk 0 ----
  {
    const float4 c0 = xyz4[sgj];
    const float4 c1 = xyz4[sgj + 64];
    sA[0][wave][lane] = make_float4(c0.x, c1.x, c0.y, c1.y);
    sB[0][wave][lane] = make_float4(c0.z, c1.z, c0.w, c1.w);
  }
  __syncthreads();

  // ---- pass A: per-lane running mins (both queries) over staged chunks ----
  float a00 = FLT_MAX, a01 = FLT_MAX, a10 = FLT_MAX, a11 = FLT_MAX;
  for (int c = 0; c < NCH; ++c) {
    const int b = c & 1;
    float4 n0, n1;
    if (c < NCH - 1) {              // issue next-chunk loads early (T14)
      n0 = xyz4[(c + 1) * KCH + sgj];
      n1 = xyz4[(c + 1) * KCH + sgj + 64];
    }
    const int cbase = c * KCH;
    #pragma unroll
    for (int ps = 0; ps < 4; ++ps) {
      const float4 a = sA[b][ps][lane];
      const float4 bb = sB[b][ps][lane];
      const float2v px = {a.x, a.y}, py = {a.z, a.w};
      const float2v pz = {bb.x, bb.y}, pw = {bb.z, bb.w};
      const float2v dot0 = pk_fma(z02, pz, pk_fma(y02, py, pk_mul(x02, px)));
      float2v d0 = pk_add(pk_sub(s02, pk_mul(two2, dot0)), pw);
      const float2v dot1 = pk_fma(z12, pz, pk_fma(y12, py, pk_mul(x12, px)));
      float2v d1 = pk_add(pk_sub(s12, pk_mul(two2, dot1)), pw);
      if (cbase + ps * 128 == ib128) {      // uniform rare branch
        if (lane == il0) {
          if (ih0) d0.y = __fadd_rn(d0.y, 1e10f);
          else     d0.x = __fadd_rn(d0.x, 1e10f);
        }
        if (lane == il1) {
          if (ih1) d1.y = __fadd_rn(d1.y, 1e10f);
          else     d1.x = __fadd_rn(d1.x, 1e10f);
        }
      }
      a00 = fminf(a00, d0.x);
      a01 = fminf(a01, d0.y);
      a10 = fminf(a10, d1.x);
      a11 = fminf(a11, d1.y);
    }
    if (c < NCH - 1) {              // LDS write late; latency hidden
      sA[b ^ 1][wave][lane] = make_float4(n0.x, n1.x, n0.y, n1.y);
      sB[b ^ 1][wave][lane] = make_float4(n0.z, n1.z, n0.w, n1.w);
    }
    __syncthreads();
  }

  // ---- two interleaved 64-lane bitonic sorts (ascending) of lane-mins ----
  float v0 = fminf(a00, a01);
  float v1 = fminf(a10, a11);
  #pragma unroll
  for (int k = 2; k <= 64; k <<= 1) {
    #pragma unroll
    for (int j = k >> 1; j > 0; j >>= 1) {
      const float o0 = __shfl_xor(v0, j, 64);
      const float o1 = __shfl_xor(v1, j, 64);
      const bool keepmin = ((lane & k) == 0) == ((lane & j) == 0);
      v0 = keepmin ? fminf(v0, o0) : fmaxf(v0, o0);
      v1 = keepmin ? fminf(v1, o1) : fmaxf(v1, o1);
    }
  }
  const float t0 = __shfl(v0, 15, 64);  // >= true 16th-smallest dist (q0)
  const float t1 = __shfl(v1, 15, 64);  // >= true 16th-smallest dist (q1)

  // ---- pass B: re-stream from LDS; survivors hit the serial insert ----
  float sd0 = FLT_MAX, sd1 = FLT_MAX;   // slot dists (lanes 0..15)
  int sj0 = 0, sj1 = 0;                 // slot indices
  float s150 = FLT_MAX, s151 = FLT_MAX; // running 16th-best (uniform)

  {
    const float4 c0 = xyz4[sgj];
    const float4 c1 = xyz4[sgj + 64];
    sA[0][wave][lane] = make_float4(c0.x, c1.x, c0.y, c1.y);
    sB[0][wave][lane] = make_float4(c0.z, c1.z, c0.w, c1.w);
  }
  __syncthreads();

  for (int c = 0; c < NCH; ++c) {
    const int b = c & 1;
    float4 n0, n1;
    if (c < NCH - 1) {
      n0 = xyz4[(c + 1) * KCH + sgj];
      n1 = xyz4[(c + 1) * KCH + sgj + 64];
    }
    const int cbase = c * KCH;

    float2v dd0[4], dd1[4];
    #pragma unroll
    for (int ps = 0; ps < 4; ++ps) {
      const float4 a = sA[b][ps][lane];
      const float4 bb = sB[b][ps][lane];
      const float2v px = {a.x, a.y}, py = {a.z, a.w};
      const float2v pz = {bb.x, bb.y}, pw = {bb.z, bb.w};
      const float2v dot0 = pk_fma(z02, pz, pk_fma(y02, py, pk_mul(x02, px)));
      dd0[ps] = pk_add(pk_sub(s02, pk_mul(two2, dot0)), pw);
      const float2v dot1 = pk_fma(z12, pz, pk_fma(y12, py, pk_mul(x12, px)));
      dd1[ps] = pk_add(pk_sub(s12, pk_mul(two2, dot1)), pw);
      if (cbase + ps * 128 == ib128) {      // uniform rare branch
        if (lane == il0) {
          if (ih0) dd0[ps].y = __fadd_rn(dd0[ps].y, 1e10f);
          else     dd0[ps].x = __fadd_rn(dd0[ps].x, 1e10f);
        }
        if (lane == il1) {
          if (ih1) dd1[ps].y = __fadd_rn(dd1[ps].y, 1e10f);
          else     dd1[ps].x = __fadd_rn(dd1[ps].x, 1e10f);
        }
      }
    }

    #pragma unroll
    for (int ps = 0; ps < 4; ++ps) {
      const int base = cbase + ps * 128;
      insert_group(dd0[ps].x, base,      t0, lane, sd0, sj0, s150);
      insert_group(dd0[ps].y, base + 64, t0, lane, sd0, sj0, s150);
      insert_group(dd1[ps].x, base,      t1, lane, sd1, sj1, s151);
      insert_group(dd1[ps].y, base + 64, t1, lane, sd1, sj1, s151);
    }

    if (c < NCH - 1) {
      sA[b ^ 1][wave][lane] = make_float4(n0.x, n1.x, n0.y, n1.y);
      sB[b ^ 1][wave][lane] = make_float4(n0.z, n1.z, n0.w, n1.w);
    }
    __syncthreads();
  }
  if (lane < 16) {
    nbr[i0 * KNN + lane] = sj0;
    nbr[i1 * KNN + lane] = sj1;
  }
}

// ---------------------------------------------------------------------------
// W1 -> Bt (transposed, n-major) bf16 hi/lo (frozen).
// ---------------------------------------------------------------------------
__global__ __launch_bounds__(256) void convert_w_kernel(
    const float* __restrict__ W1, short* __restrict__ bhi,
    short* __restrict__ blo) {
  const int n = blockIdx.x;      // 0..511
  const int k = threadIdx.x;     // 0..255
  const float v = (n < 256) ? W1[k * DTOK + n]
                            : W1[(259 + k) * DTOK + (n - 256)];
  short h = f2bf(v);
  bhi[n * 256 + k] = h;
  blo[n * 256 + k] = f2bf(v - bf2f(h));
}

// ---------------------------------------------------------------------------
// pq GEMM v2 (frozen from R9).
// ---------------------------------------------------------------------------
__global__ __launch_bounds__(256, 2) void pq_gemm_fused_kernel(
    const float* __restrict__ A, const short* __restrict__ Bthi,
    const short* __restrict__ Btlo, const float* __restrict__ xyz,
    const float* __restrict__ W1, const float* __restrict__ b1,
    float* __restrict__ R, float* __restrict__ Q) {
  __shared__ short Ahi[64][32], Alo[64][32];    // 4K + 4K
  __shared__ short Bhi[128][32], Blo[128][32];  // 8K + 8K
  __shared__ float Qs[64][65];                  // 16.6K
  __shared__ float sx[64][3];
  __shared__ float swz[6][64];
  __shared__ float sb1[64];

  const int tid = threadIdx.x;
  const int lane = tid & 63;
  const int wave = tid >> 6;
  const int l15 = lane & 15;
  const int quad = lane >> 4;
  const int mh = wave & 1;
  const int qh = wave >> 1;
  const int m0 = blockIdx.x * 64;
  const int np0 = blockIdx.y * 64;

  if (tid < 64) {
    sx[tid][0] = xyz[(m0 + tid) * 3];
    sx[tid][1] = xyz[(m0 + tid) * 3 + 1];
    sx[tid][2] = xyz[(m0 + tid) * 3 + 2];
  } else if (tid < 128) {
    int n = tid - 64;
    sb1[n] = b1[np0 + n];
    #pragma unroll
    for (int r = 0; r < 3; ++r) {
      swz[r][n] = W1[(256 + r) * DTOK + np0 + n];
      swz[3 + r][n] = W1[(515 + r) * DTOK + np0 + n];
    }
  }

  float4v acc[2][4];
  #pragma unroll
  for (int mf = 0; mf < 2; ++mf)
    #pragma unroll
    for (int nf = 0; nf < 4; ++nf)
      #pragma unroll
      for (int e = 0; e < 4; ++e) acc[mf][nf][e] = 0.f;

  const int ar = tid >> 2;             // A staging row 0..63
  const int ak = (tid & 3) * 8;        // A staging k-offset

  #pragma unroll 1
  for (int kc = 0; kc < 8; ++kc) {
    const int k0 = kc * 32;
    __syncthreads();
    {
      const float* asrc = A + (size_t)(m0 + ar) * 256 + k0 + ak;
      float4 a0 = *(const float4*)asrc;
      float4 a1 = *(const float4*)(asrc + 4);
      float v[8] = {a0.x, a0.y, a0.z, a0.w, a1.x, a1.y, a1.z, a1.w};
      short8 h8, l8;
      #pragma unroll
      for (int e = 0; e < 8; ++e) {
        short h = f2bf(v[e]);
        h8[e] = h;
        l8[e] = f2bf(v[e] - bf2f(h));
      }
      *(short8*)(&Ahi[ar][ak]) = h8;
      *(short8*)(&Alo[ar][ak]) = l8;
    }
    #pragma unroll
    for (int l = 0; l < 4; ++l) {
      const int rem = tid + 256 * (l & 1);
      const int row = rem >> 2;
      const int koff = (rem & 3) * 8;
      const int n = (row < 64) ? (np0 + row) : (256 + np0 + row - 64);
      const short* src = ((l < 2) ? Bthi : Btlo) + (size_t)n * 256 + k0 + koff;
      short8 vv = *(const short8*)src;
      if (l < 2) *(short8*)(&Bhi[row][koff]) = vv;
      else       *(short8*)(&Blo[row][koff]) = vv;
    }
    __syncthreads();

    short8 ah[2], al[2], bh[4], bl[4];
    #pragma unroll
    for (int mf = 0; mf < 2; ++mf) {
      ah[mf] = *(const short8*)(&Ahi[mh * 32 + mf * 16 + l15][quad * 8]);
      al[mf] = *(const short8*)(&Alo[mh * 32 + mf * 16 + l15][quad * 8]);
    }
    #pragma unroll
    for (int nf = 0; nf < 4; ++nf) {
      bh[nf] = *(const short8*)(&Bhi[qh * 64 + nf * 16 + l15][quad * 8]);
      bl[nf] = *(const short8*)(&Blo[qh * 64 + nf * 16 + l15][quad * 8]);
    }
    #pragma unroll
    for (int mf = 0; mf < 2; ++mf)
      #pragma unroll
      for (int nf = 0; nf < 4; ++nf) {
        acc[mf][nf] = __builtin_amdgcn_mfma_f32_16x16x32_bf16(
            ah[mf], bh[nf], acc[mf][nf], 0, 0, 0);
        acc[mf][nf] = __builtin_amdgcn_mfma_f32_16x16x32_bf16(
            ah[mf], bl[nf], acc[mf][nf], 0, 0, 0);
        acc[mf][nf] = __builtin_amdgcn_mfma_f32_16x16x32_bf16(
            al[mf], bh[nf], acc[mf][nf], 0, 0, 0);
      }
  }

  if (qh == 1) {
    #pragma unroll
    for (int mf = 0; mf < 2; ++mf)
      #pragma unroll
      for (int nf = 0; nf < 4; ++nf)
        #pragma unroll
        for (int e = 0; e < 4; ++e) {
          int row = mh * 32 + mf * 16 + quad * 4 + e;
          int col = nf * 16 + l15;
          float q = acc[mf][nf][e] + sx[row][0] * swz[3][col] +
                    sx[row][1] * swz[4][col] + sx[row][2] * swz[5][col];
          Qs[row][col] = q;
          Q[(size_t)(m0 + row) * DTOK + np0 + col] = q;
        }
  }
  __syncthreads();
  if (qh == 0) {
    #pragma unroll
    for (int mf = 0; mf < 2; ++mf)
      #pragma unroll
      for (int nf = 0; nf < 4; ++nf)
        #pragma unroll
        for (int e = 0; e < 4; ++e) {
          int row = mh * 32 + mf * 16 + quad * 4 + e;
          int col = nf * 16 + l15;
          float p = acc[mf][nf][e] + sx[row][0] * swz[0][col] +
                    sx[row][1] * swz[1][col] + sx[row][2] * swz[2][col];
          R[(size_t)(m0 + row) * DTOK + np0 + col] =
              (p + sb1[col]) - Qs[row][col];
        }
  }
}

// ---------------------------------------------------------------------------
// EdgeConv via MFMA (EXACT R10 version -- R11's global-B variant regressed
// 68 -> ~110 us/launch; W2 register fragments restored).
// ---------------------------------------------------------------------------
#define EP 8          // points per group

__global__ __launch_bounds__(256, 2) void edge_mfma_kernel(
    const float* __restrict__ R, const float* __restrict__ Q,
    const int* __restrict__ nbr, const float* __restrict__ W2,
    const float* __restrict__ b2, float* __restrict__ out,
    int num_groups, int groups_per_block) {
  __shared__ short Hs[EP * KNN * DTOK];   // 128 rows x 256, 64 KB
  const int lane = threadIdx.x & 63;
  const int wave = threadIdx.x >> 6;
  const int l15 = lane & 15;
  const int quad = lane >> 4;

  short8 bfr[4][8];
  #pragma unroll
  for (int nt_i = 0; nt_i < 4; ++nt_i) {
    const int n = (wave * 4 + nt_i) * 16 + l15;
    #pragma unroll
    for (int kt = 0; kt < 8; ++kt) {
      short8 f;
      #pragma unroll
      for (int jj = 0; jj < 8; ++jj) {
        int k = kt * 32 + quad * 8 + jj;
        f[jj] = f2bf(W2[k * DTOK + n]);
      }
      bfr[nt_i][kt] = f;
    }
  }

  const int wc8 = lane >> 1;
  const int wsub = (lane & 1) * 4;

  for (int gi = 0; gi < groups_per_block; ++gi) {
    const int g = blockIdx.x + gi * gridDim.x;
    if (g >= num_groups) break;
    const int i0 = g * EP;

    // ---- build H: prefetched nbr via lane reg + shfl, pipelined gathers ----
    {
      const int ia = i0 + wave * 2;
      const int jr0 = nbr[ia * KNN + l15];
      const int jr1 = nbr[(ia + 1) * KNN + l15];
      const float4 ri0 = ((const float4*)(R + (size_t)ia * DTOK))[lane];
      const float4 ri1 = ((const float4*)(R + (size_t)(ia + 1) * DTOK))[lane];
      #pragma unroll
      for (int pp = 0; pp < 2; ++pp) {
        const float4 ri = pp ? ri1 : ri0;
        const int jr = pp ? jr1 : jr0;
        #pragma unroll
        for (int k = 0; k < KNN; ++k) {
          const int j = __shfl(jr, k, 16);
          const float4 qj = ((const float4*)(Q + (size_t)j * DTOK))[lane];
          const int r = wave * 32 + pp * 16 + k;
          uint2 pk;
          pk.x = ((unsigned)(unsigned short)f2bf(fmaxf(ri.x + qj.x, 0.f))) |
                 (((unsigned)(unsigned short)f2bf(fmaxf(ri.y + qj.y, 0.f))) << 16);
          pk.y = ((unsigned)(unsigned short)f2bf(fmaxf(ri.z + qj.z, 0.f))) |
                 (((unsigned)(unsigned short)f2bf(fmaxf(ri.w + qj.w, 0.f))) << 16);
          *(uint2*)(&Hs[r * DTOK + ((wc8 ^ (r & 7)) << 3) + wsub]) = pk;
        }
      }
    }
    __syncthreads();

    #pragma unroll
    for (int mp = 0; mp < 4; ++mp) {
      float4v acc[2][4];
      #pragma unroll
      for (int mi = 0; mi < 2; ++mi)
        #pragma unroll
        for (int nt_i = 0; nt_i < 4; ++nt_i)
          #pragma unroll
          for (int e = 0; e < 4; ++e) acc[mi][nt_i][e] = 0.f;

      #pragma unroll
      for (int kt = 0; kt < 8; ++kt) {
        const int pc = ((kt * 4 + quad) ^ (l15 & 7)) << 3;
        const short8 a0 = *(const short8*)(
            &Hs[((mp * 2 + 0) * 16 + l15) * DTOK + pc]);
        const short8 a1 = *(const short8*)(
            &Hs[((mp * 2 + 1) * 16 + l15) * DTOK + pc]);
        #pragma unroll
        for (int nt_i = 0; nt_i < 4; ++nt_i) {
          acc[0][nt_i] = __builtin_amdgcn_mfma_f32_16x16x32_bf16(
              a0, bfr[nt_i][kt], acc[0][nt_i], 0, 0, 0);
          acc[1][nt_i] = __builtin_amdgcn_mfma_f32_16x16x32_bf16(
              a1, bfr[nt_i][kt], acc[1][nt_i], 0, 0, 0);
        }
      }

      #pragma unroll
      for (int mi = 0; mi < 2; ++mi) {
        #pragma unroll
        for (int nt_i = 0; nt_i < 4; ++nt_i) {
          float rm = fmaxf(fmaxf(acc[mi][nt_i][0], acc[mi][nt_i][1]),
                           fmaxf(acc[mi][nt_i][2], acc[mi][nt_i][3]));
          rm = fmaxf(rm, __shfl_xor(rm, 16, 64));
          rm = fmaxf(rm, __shfl_xor(rm, 32, 64));
          if (lane < 16) {
            const int i = i0 + mp * 2 + mi;
            const int n = (wave * 4 + nt_i) * 16 + lane;
            out[(size_t)i * DTOK + n] = rm + b2[n];
          }
        }
      }
    }
    __syncthreads();
  }
}

// ---------------------------------------------------------------------------
extern "C" void kernel_launch(void* const* d_in, const int* in_sizes, int n_in,
                              void* d_out, int out_size, void* d_ws,
                              size_t ws_size, hipStream_t stream) {
  const float* xyz = (const float*)d_in[0];
  const float* feat = (const float*)d_in[1];
  const float* W1a = (const float*)d_in[2];
  const float* b1a = (const float*)d_in[3];
  const float* W2a = (const float*)d_in[4];
  const float* b2a = (const float*)d_in[5];
  const float* W1b = (const float*)d_in[6];
  const float* b1b = (const float*)d_in[7];
  const float* W2b = (const float*)d_in[8];
  const float* b2b = (const float*)d_in[9];
  float* out = (float*)d_out;

  // ws layout (~25 MB): nbr 0.5 | xyz4 128KB (then R at +8MB) | Q | Bt hi/lo
  char* w = (char*)d_ws;
  const size_t SZ_NBR = (size_t)N_PTS * KNN * sizeof(int);        // 512 KB
  const size_t MB = 1024 * 1024;
  int* nbr = (int*)w;
  char* w1 = w + SZ_NBR;
  float4* xyz4 = (float4*)w1;                  // 128 KB
  float* R = (float*)(w1 + 8 * MB);            // 8 MB
  float* Q = (float*)(w + SZ_NBR + 16 * MB);   // 8 MB
  short* Bthi = (short*)(w + SZ_NBR + 24 * MB);// 256 KB
  short* Btlo = Bthi + 512 * 256;              // 256 KB
  float* bufC = out;                           // layer-a output staging

  knn_prep_kernel<<<N_PTS / 256, 256, 0, stream>>>(xyz, xyz4);
  knn_select_kernel<<<N_PTS / 8, 256, 0, stream>>>(xyz4, nbr);

  const int num_groups = N_PTS / EP;           // 1024
  const int nblocks = 512;

  // layer a
  convert_w_kernel<<<512, 256, 0, stream>>>(W1a, Bthi, Btlo);
  pq_gemm_fused_kernel<<<dim3(N_PTS / 64, 4), 256, 0, stream>>>(
      feat, Bthi, Btlo, xyz, W1a, b1a, R, Q);
  edge_mfma_kernel<<<nblocks, 256, 0, stream>>>(R, Q, nbr, W2a, b2a, bufC,
                                                num_groups, 2);

  // layer b
  convert_w_kernel<<<512, 256, 0, stream>>>(W1b, Bthi, Btlo);
  pq_gemm_fused_kernel<<<dim3(N_PTS / 64, 4), 256, 0, stream>>>(
      bufC, Bthi, Btlo, xyz, W1b, b1b, R, Q);
  edge_mfma_kernel<<<nblocks, 256, 0, stream>>>(R, Q, nbr, W2b, b2b, out,
                                                num_groups, 2);
}